// Round 9
// baseline (56140.503 us; speedup 1.0000x reference)
//
#include <hip/hip_runtime.h>

// Problem constants
constexpr int Bsz = 256, Lf = 14, Tt = 500, Hn = 1000;
constexpr int HP = 1024, KP = 1024;     // padded h/k extents
constexpr int NBLK = 256;

// ---- MFMA-path d_ws layout ----
constexpr size_t W_MAT    = (size_t)HP * KP * 2;        // 2 MB bf16 per matrix
constexpr size_t W_SH     = (size_t)HP * KP;            // shorts per matrix
constexpr size_t SB_OFF   = 5 * W_MAT;                  // 10,485,760
constexpr size_t SB_BYTES = (size_t)2 * 3 * Bsz * KP;   // 1,572,864
constexpr size_t BAR_OFF  = SB_OFF + SB_BYTES;          // 12,058,624
constexpr size_t WS_NEED  = BAR_OFF + 4096;             // barrier area 4 KB

// ---- fallback (round-5 VALU) layout: spikes at 0, bar after ----
constexpr size_t FB_SB_BYTES = (size_t)2 * 3 * Bsz * KP;
constexpr size_t FB_SMEM     = 98304;
constexpr int    FB_NBLK     = 250;

typedef __attribute__((ext_vector_type(8)))  short    short8;  // 8 bf16
typedef __attribute__((ext_vector_type(16))) float    f32x16;
typedef __attribute__((ext_vector_type(2)))  unsigned u32x2;
typedef __attribute__((ext_vector_type(4)))  unsigned u32x4v;

// ======================= prep kernel (bf16 weights) =======================
__device__ __forceinline__ unsigned short f2bf(float f) {
  unsigned u = __builtin_bit_cast(unsigned, f);
  unsigned r = (u + 0x7FFFu + ((u >> 16) & 1u)) >> 16;   // RNE
  return (unsigned short)r;
}

__global__ void prep_w(const float* __restrict__ R1, const float* __restrict__ W2,
                       const float* __restrict__ R2, const float* __restrict__ W3,
                       const float* __restrict__ R3, unsigned char* __restrict__ ws) {
  int id  = blockIdx.x * 256 + threadIdx.x;      // 5 * 2^20 threads
  int mat = id >> 20;
  int rem = id & 0xFFFFF;
  int h   = rem >> 10;
  int k   = rem & 1023;
  const float* src = (mat == 0) ? R1 : (mat == 1) ? W2 : (mat == 2) ? R2
                    : (mat == 3) ? W3 : R3;
  float v = (h < Hn && k < Hn) ? src[(size_t)h * Hn + k] : 0.f;
  ((unsigned short*)ws)[(size_t)mat * W_SH + (size_t)h * KP + k] = f2bf(v);
}

// ======================= MFMA main kernel =======================
__device__ __forceinline__ short8 expand8(u32x2 d) {
  // 8 spike bytes (0/1) -> 8 bf16 (0.0/1.0). pair = b0 | b1<<16; *0x3F80.
  unsigned p0 = __umul24(((d[0] & 0xFFu)         | ((d[0] & 0xFF00u) << 8)), 0x3F80u);
  unsigned p1 = __umul24((((d[0] >> 16) & 0xFFu) | ((d[0] >> 24) << 16)),    0x3F80u);
  unsigned p2 = __umul24(((d[1] & 0xFFu)         | ((d[1] & 0xFF00u) << 8)), 0x3F80u);
  unsigned p3 = __umul24((((d[1] >> 16) & 0xFFu) | ((d[1] >> 24) << 16)),    0x3F80u);
  u32x4v u = {p0, p1, p2, p3};
  return __builtin_bit_cast(short8, u);
}

__device__ __forceinline__ f32x16 MF(short8 a, const unsigned short* wp, f32x16 c) {
  short8 b = *(const short8*)wp;
  return __builtin_amdgcn_mfma_f32_32x32x16_bf16(a, b, c, 0, 0, 0);
}

__global__ void __launch_bounds__(256, 1)
snn_mfma(const float* __restrict__ x, const float* __restrict__ W1,
         unsigned char* __restrict__ ws, float* __restrict__ out)
{
  __shared__ float redF[10240];   // [0,9216): 9 C-tiles as [j][lane]; [9216,10240): F

  const int tid = threadIdx.x;
  const int l   = tid & 63;
  const int w   = tid >> 6;                    // wave 0..3 (k-split)
  const int lr  = l & 31;                      // A-row (b) / B-col (h)
  const int lg  = l >> 5;                      // k lane-group
  const int blk = blockIdx.x;
  const int bt  = blk >> 5;                            // 0..7
  const int ht  = (blk & 7) * 4 + ((blk >> 3) & 3);    // 0..31 (XCD-grouped)
  const int b0  = bt * 32, h0 = ht * 32;

  unsigned char* sb  = ws + SB_OFF;
  unsigned*      bar = (unsigned*)(ws + BAR_OFF);
  // barrier area: leaf[g] at bar+16*g (16 lines), root at bar+256, release at bar+272

  // per-lane bf16 weight fragment pointers: row h0+lr, k offset lg*8
  const unsigned short* wb = (const unsigned short*)ws;
  const size_t wlane = (size_t)(h0 + lr) * KP + lg * 8;
  const unsigned short* wR1 = wb + 0 * W_SH + wlane;
  const unsigned short* wW2 = wb + 1 * W_SH + wlane;
  const unsigned short* wR2 = wb + 2 * W_SH + wlane;
  const unsigned short* wW3 = wb + 3 * W_SH + wlane;
  const unsigned short* wR3 = wb + 4 * W_SH + wlane;

  // W1 rows for feedforward (one h-col per thread), hoisted
  float w1r[Lf];
  {
    int h = h0 + (tid & 31);
#pragma unroll
    for (int t = 0; t < Lf; ++t)
      w1r[t] = (h < Hn) ? W1[(size_t)h * Lf + t] : 0.f;
  }

  f32x16 v1, v2, v3;
#pragma unroll
  for (int j = 0; j < 16; ++j) { v1[j] = 0.f; v2[j] = 0.f; v3[j] = 0.f; }

#pragma unroll 1
  for (int p = 0; p < Tt + 2; ++p) {
    const int srd = (p + 1) & 1;
    const int swr = p & 1;

    // ---- feedforward F = x@W1^T tile into LDS (layer 1, t=p) ----
    if (p < Tt) {
#pragma unroll
      for (int q = 0; q < 4; ++q) {
        int fb = (tid >> 5) + 8 * q;
        const float* xr = x + (size_t)(b0 + fb) * Lf * Tt + p;
        float F = 0.f;
#pragma unroll
        for (int t = 0; t < Lf; ++t) F = fmaf(xr[(size_t)t * Tt], w1r[t], F);
        redF[9216 + fb * 32 + (tid & 31)] = F;
      }
    } else {
#pragma unroll
      for (int q = 0; q < 4; ++q)
        redF[9216 + ((tid >> 5) + 8 * q) * 32 + (tid & 31)] = 0.f;
    }

    // ---- MFMA: 3 diagonal layers, k-split across waves ----
    f32x16 acc1, acc2, acc3;
#pragma unroll
    for (int j = 0; j < 16; ++j) { acc1[j] = 0.f; acc2[j] = 0.f; acc3[j] = 0.f; }

    const unsigned char* sA = sb + ((size_t)(srd * 3 + 0) * Bsz + (b0 + lr)) * KP + lg * 8;
    const unsigned char* sB = sb + ((size_t)(srd * 3 + 1) * Bsz + (b0 + lr)) * KP + lg * 8;
    const unsigned char* sC = sb + ((size_t)(srd * 3 + 2) * Bsz + (b0 + lr)) * KP + lg * 8;

#pragma unroll
    for (int half = 0; half < 2; ++half) {
      const int kbb = w * 16 + half * 8;
      const unsigned char* pA = sA + kbb * 16;
      const unsigned char* pB = sB + kbb * 16;
      const unsigned char* pC = sC + kbb * 16;
      u32x2 dA[8], dB[8], dC[8];
      asm volatile(
        "global_load_dwordx2 %0, %24, off sc0 sc1\n\t"
        "global_load_dwordx2 %8, %25, off sc0 sc1\n\t"
        "global_load_dwordx2 %16, %26, off sc0 sc1\n\t"
        "global_load_dwordx2 %1, %24, off offset:16 sc0 sc1\n\t"
        "global_load_dwordx2 %9, %25, off offset:16 sc0 sc1\n\t"
        "global_load_dwordx2 %17, %26, off offset:16 sc0 sc1\n\t"
        "global_load_dwordx2 %2, %24, off offset:32 sc0 sc1\n\t"
        "global_load_dwordx2 %10, %25, off offset:32 sc0 sc1\n\t"
        "global_load_dwordx2 %18, %26, off offset:32 sc0 sc1\n\t"
        "global_load_dwordx2 %3, %24, off offset:48 sc0 sc1\n\t"
        "global_load_dwordx2 %11, %25, off offset:48 sc0 sc1\n\t"
        "global_load_dwordx2 %19, %26, off offset:48 sc0 sc1\n\t"
        "global_load_dwordx2 %4, %24, off offset:64 sc0 sc1\n\t"
        "global_load_dwordx2 %12, %25, off offset:64 sc0 sc1\n\t"
        "global_load_dwordx2 %20, %26, off offset:64 sc0 sc1\n\t"
        "global_load_dwordx2 %5, %24, off offset:80 sc0 sc1\n\t"
        "global_load_dwordx2 %13, %25, off offset:80 sc0 sc1\n\t"
        "global_load_dwordx2 %21, %26, off offset:80 sc0 sc1\n\t"
        "global_load_dwordx2 %6, %24, off offset:96 sc0 sc1\n\t"
        "global_load_dwordx2 %14, %25, off offset:96 sc0 sc1\n\t"
        "global_load_dwordx2 %22, %26, off offset:96 sc0 sc1\n\t"
        "global_load_dwordx2 %7, %24, off offset:112 sc0 sc1\n\t"
        "global_load_dwordx2 %15, %25, off offset:112 sc0 sc1\n\t"
        "global_load_dwordx2 %23, %26, off offset:112 sc0 sc1\n\t"
        "s_waitcnt vmcnt(0)"
        : "=&v"(dA[0]), "=&v"(dA[1]), "=&v"(dA[2]), "=&v"(dA[3]),
          "=&v"(dA[4]), "=&v"(dA[5]), "=&v"(dA[6]), "=&v"(dA[7]),
          "=&v"(dB[0]), "=&v"(dB[1]), "=&v"(dB[2]), "=&v"(dB[3]),
          "=&v"(dB[4]), "=&v"(dB[5]), "=&v"(dB[6]), "=&v"(dB[7]),
          "=&v"(dC[0]), "=&v"(dC[1]), "=&v"(dC[2]), "=&v"(dC[3]),
          "=&v"(dC[4]), "=&v"(dC[5]), "=&v"(dC[6]), "=&v"(dC[7])
        : "v"(pA), "v"(pB), "v"(pC)
        : "memory");
      __builtin_amdgcn_sched_barrier(0);

#pragma unroll
      for (int i = 0; i < 8; ++i) {
        const int ko = (kbb + i) * 16;   // element offset into weight rows
        short8 a0 = expand8(dA[i]);
        short8 a1 = expand8(dB[i]);
        short8 a2 = expand8(dC[i]);
        acc1 = MF(a0, wR1 + ko, acc1);
        acc2 = MF(a0, wW2 + ko, acc2);
        acc2 = MF(a1, wR2 + ko, acc2);
        acc3 = MF(a1, wW3 + ko, acc3);
        acc3 = MF(a2, wR3 + ko, acc3);
      }
    }

    // ---- cross-wave reduce (conflict-free [j][lane] layout) + LIF (wave 0) ----
    if (w != 0) {
      float* dp = &redF[(w - 1) * 3 * 1024 + l];
#pragma unroll
      for (int j = 0; j < 16; ++j) {
        dp[j * 64]        = acc1[j];
        dp[1024 + j * 64] = acc2[j];
        dp[2048 + j * 64] = acc3[j];
      }
    }
    __syncthreads();

    if (w == 0) {
#pragma unroll
      for (int ww = 0; ww < 3; ++ww) {
        const float* ps = &redF[ww * 3 * 1024 + l];
#pragma unroll
        for (int j = 0; j < 16; ++j) {
          acc1[j] += ps[j * 64];
          acc2[j] += ps[1024 + j * 64];
          acc3[j] += ps[2048 + j * 64];
        }
      }
      unsigned char* o1 = sb + ((size_t)(swr * 3 + 0) * Bsz + b0) * KP + h0 + lr;
      unsigned char* o2 = sb + ((size_t)(swr * 3 + 1) * Bsz + b0) * KP + h0 + lr;
      unsigned char* o3 = sb + ((size_t)(swr * 3 + 2) * Bsz + b0) * KP + h0 + lr;
#pragma unroll
      for (int j = 0; j < 16; ++j) {
        const int row = (j & 3) + 8 * (j >> 2) + 4 * lg;   // C-tile b-row
        float F   = redF[9216 + row * 32 + lr];
        float vn1 = 0.5f * (v1[j] + acc1[j] + F);
        unsigned c1 = (vn1 >= 1.0f) ? 1u : 0u;
        v1[j] = c1 ? 0.f : vn1;
        asm volatile("global_store_byte %0, %1, off sc0 sc1"
                     :: "v"(o1 + (size_t)row * KP), "v"(c1) : "memory");
        float vn2 = 0.5f * (v2[j] + acc2[j]);
        unsigned c2 = (vn2 >= 1.0f) ? 1u : 0u;
        v2[j] = c2 ? 0.f : vn2;
        asm volatile("global_store_byte %0, %1, off sc0 sc1"
                     :: "v"(o2 + (size_t)row * KP), "v"(c2) : "memory");
        float vn3 = 0.5f * (v3[j] + acc3[j]);
        unsigned c3 = (vn3 >= 1.0f) ? 1u : 0u;
        v3[j] = c3 ? 0.f : vn3;
        asm volatile("global_store_byte %0, %1, off sc0 sc1"
                     :: "v"(o3 + (size_t)row * KP), "v"(c3) : "memory");
      }
    }

    // ---- tree barrier: 16 leaf lines -> root line -> read-only release line ----
    asm volatile("s_waitcnt vmcnt(0)" ::: "memory");  // own stores visible first
    __syncthreads();
    if (tid == 0) {
      unsigned* leaf = bar + (blk >> 4) * 16;   // 16 groups of 16 blocks, 64B apart
      unsigned v = __hip_atomic_fetch_add(leaf, 1u, __ATOMIC_RELAXED,
                                          __HIP_MEMORY_SCOPE_AGENT);
      if ((v & 15u) == 15u) {                   // last of group this phase
        unsigned r = __hip_atomic_fetch_add(bar + 256, 1u, __ATOMIC_RELAXED,
                                            __HIP_MEMORY_SCOPE_AGENT);
        if ((r & 15u) == 15u) {                 // last group: publish release
          __hip_atomic_store(bar + 272, (unsigned)(p + 1), __ATOMIC_RELAXED,
                             __HIP_MEMORY_SCOPE_AGENT);
        }
      }
      while (__hip_atomic_load(bar + 272, __ATOMIC_RELAXED,
                               __HIP_MEMORY_SCOPE_AGENT) < (unsigned)(p + 1))
        __builtin_amdgcn_s_sleep(8);            // ~512cy backoff, read-only line
    }
    __syncthreads();
  }

  // ---- output: exp(final v3) ----
  if (w == 0 && (h0 + lr) < Hn) {
#pragma unroll
    for (int j = 0; j < 16; ++j) {
      const int row = (j & 3) + 8 * (j >> 2) + 4 * lg;
      out[(size_t)(b0 + row) * Hn + h0 + lr] = expf(v3[j]);
    }
  }
}

// ======================= fallback: round-5 VALU kernel =======================
__device__ __forceinline__ size_t fb_srow(int slot, int layer, int b) {
  return (((size_t)slot * 3 + layer) * Bsz + b) * KP;
}
__device__ __forceinline__ void fb_cvt4(unsigned w, float* s) {
  s[0] = (float)(w & 0xffu);
  s[1] = (float)((w >> 8) & 0xffu);
  s[2] = (float)((w >> 16) & 0xffu);
  s[3] = (float)(w >> 24);
}
__device__ __forceinline__ void fb_load64(const unsigned char* p, u32x4v sp[4]) {
  asm volatile(
      "global_load_dwordx4 %0, %4, off sc0 sc1\n\t"
      "global_load_dwordx4 %1, %4, off offset:16 sc0 sc1\n\t"
      "global_load_dwordx4 %2, %4, off offset:32 sc0 sc1\n\t"
      "global_load_dwordx4 %3, %4, off offset:48 sc0 sc1\n\t"
      "s_waitcnt vmcnt(0)"
      : "=&v"(sp[0]), "=&v"(sp[1]), "=&v"(sp[2]), "=&v"(sp[3])
      : "v"(p) : "memory");
}
__device__ __forceinline__ void fb_load40(const unsigned char* p,
                                          u32x4v& a, u32x4v& b, u32x2& c) {
  asm volatile(
      "global_load_dwordx4 %0, %3, off sc0 sc1\n\t"
      "global_load_dwordx4 %1, %3, off offset:16 sc0 sc1\n\t"
      "global_load_dwordx2 %2, %3, off offset:32 sc0 sc1\n\t"
      "s_waitcnt vmcnt(0)"
      : "=&v"(a), "=&v"(b), "=&v"(c) : "v"(p) : "memory");
}
__device__ __forceinline__ void fb_store4(unsigned char* p, unsigned v) {
  asm volatile("global_store_dword %0, %1, off sc0 sc1"
               :: "v"(p), "v"(v) : "memory");
}
__device__ __forceinline__ void fb_fmac16(float acc[4], u32x4v sw,
                                          const float* __restrict__ wr) {
  float s[16];
  fb_cvt4(sw[0], s); fb_cvt4(sw[1], s + 4); fb_cvt4(sw[2], s + 8); fb_cvt4(sw[3], s + 12);
#pragma unroll
  for (int j = 0; j < 4; ++j) {
    const float4* w4 = (const float4*)(wr + (size_t)j * Hn);
    float4 wa = w4[0], wb = w4[1], wc = w4[2], wd = w4[3];
    acc[j] = fmaf(wa.x, s[0],  acc[j]);  acc[j] = fmaf(wa.y, s[1],  acc[j]);
    acc[j] = fmaf(wa.z, s[2],  acc[j]);  acc[j] = fmaf(wa.w, s[3],  acc[j]);
    acc[j] = fmaf(wb.x, s[4],  acc[j]);  acc[j] = fmaf(wb.y, s[5],  acc[j]);
    acc[j] = fmaf(wb.z, s[6],  acc[j]);  acc[j] = fmaf(wb.w, s[7],  acc[j]);
    acc[j] = fmaf(wc.x, s[8],  acc[j]);  acc[j] = fmaf(wc.y, s[9],  acc[j]);
    acc[j] = fmaf(wc.z, s[10], acc[j]);  acc[j] = fmaf(wc.w, s[11], acc[j]);
    acc[j] = fmaf(wd.x, s[12], acc[j]);  acc[j] = fmaf(wd.y, s[13], acc[j]);
    acc[j] = fmaf(wd.z, s[14], acc[j]);  acc[j] = fmaf(wd.w, s[15], acc[j]);
  }
}
__device__ __forceinline__ void fb_fmac8(float acc[4], u32x2 sw,
                                         const float* __restrict__ wr) {
  float s[8];
  fb_cvt4(sw[0], s); fb_cvt4(sw[1], s + 4);
#pragma unroll
  for (int j = 0; j < 4; ++j) {
    const float4* w4 = (const float4*)(wr + (size_t)j * Hn);
    float4 wa = w4[0], wb = w4[1];
    acc[j] = fmaf(wa.x, s[0], acc[j]);  acc[j] = fmaf(wa.y, s[1], acc[j]);
    acc[j] = fmaf(wa.z, s[2], acc[j]);  acc[j] = fmaf(wa.w, s[3], acc[j]);
    acc[j] = fmaf(wb.x, s[4], acc[j]);  acc[j] = fmaf(wb.y, s[5], acc[j]);
    acc[j] = fmaf(wb.z, s[6], acc[j]);  acc[j] = fmaf(wb.w, s[7], acc[j]);
  }
}
__device__ __forceinline__ void fb_accum(float acc[4],
    const unsigned char* __restrict__ srow,
    const float* __restrict__ wrow, int k0, int k1) {
  int kc = k0;
  for (; kc + 64 <= k1; kc += 64) {
    u32x4v sp[4];
    fb_load64(srow + kc, sp);
#pragma unroll
    for (int c = 0; c < 4; ++c)
      fb_fmac16(acc, sp[c], wrow + kc + c * 16);
  }
  if (kc < k1) {
    u32x4v a, b; u32x2 c2;
    fb_load40(srow + kc, a, b, c2);
    fb_fmac16(acc, a, wrow + kc);
    fb_fmac16(acc, b, wrow + kc + 16);
    fb_fmac8(acc, c2, wrow + kc + 32);
  }
}
__device__ __forceinline__ unsigned fb_lif(float v[4], const float a[4]) {
  unsigned pack = 0;
#pragma unroll
  for (int j = 0; j < 4; ++j) {
    float vn = v[j] + (a[j] - v[j]) * 0.5f;
    bool sp = (vn >= 1.0f);
    v[j] = sp ? 0.0f : vn;
    pack |= (sp ? 1u : 0u) << (8 * j);
  }
  return pack;
}

__global__ void __launch_bounds__(1024, 4)
snn_fb(const float* __restrict__ x,
       const float* __restrict__ W1, const float* __restrict__ R1,
       const float* __restrict__ W2, const float* __restrict__ R2,
       const float* __restrict__ W3, const float* __restrict__ R3,
       unsigned char* __restrict__ sb, unsigned* __restrict__ bar,
       float* __restrict__ out)
{
  extern __shared__ float4 red[];
  const int tid = threadIdx.x;
  const int b   = tid & 255;
  const int ks  = __builtin_amdgcn_readfirstlane(tid >> 8);
  const int h0  = blockIdx.x * 4;
  const int k0  = ks * 256;
  const int k1  = (ks == 3) ? Hn : (k0 + 256);

  const float* W1r = W1 + (size_t)h0 * Lf;
  const float* R1r = R1 + (size_t)h0 * Hn;
  const float* W2r = W2 + (size_t)h0 * Hn;
  const float* R2r = R2 + (size_t)h0 * Hn;
  const float* W3r = W3 + (size_t)h0 * Hn;
  const float* R3r = R3 + (size_t)h0 * Hn;

  float v1[4], v2[4], v3[4];
#pragma unroll
  for (int j = 0; j < 4; ++j) { v1[j] = 0.f; v2[j] = 0.f; v3[j] = 0.f; }
  const float* xb = x + (size_t)b * (Lf * Tt);

  for (int p = 0; p < Tt + 2; ++p) {
    const int srd = (p + 1) & 1;
    const int swr = p & 1;
    float a1[4] = {0,0,0,0}, a2[4] = {0,0,0,0}, a3[4] = {0,0,0,0};
    const bool l1on = (p < Tt), l2on = (p >= 1) && (p <= Tt), l3on = (p >= 2);

    if (l1on) {
      if (ks == 3) {
#pragma unroll
        for (int t = 0; t < Lf; ++t) {
          float xv = xb[(size_t)t * Tt + p];
#pragma unroll
          for (int j = 0; j < 4; ++j) a1[j] = fmaf(W1r[j * Lf + t], xv, a1[j]);
        }
      }
      fb_accum(a1, sb + fb_srow(srd, 0, b), R1r, k0, k1);
    }
    if (l2on) {
      fb_accum(a2, sb + fb_srow(srd, 0, b), W2r, k0, k1);
      fb_accum(a2, sb + fb_srow(srd, 1, b), R2r, k0, k1);
    }
    if (l3on) {
      fb_accum(a3, sb + fb_srow(srd, 1, b), W3r, k0, k1);
      fb_accum(a3, sb + fb_srow(srd, 2, b), R3r, k0, k1);
    }

    if (ks != 0) {
      if (l1on) red[(0 * 3 + ks - 1) * Bsz + b] = make_float4(a1[0], a1[1], a1[2], a1[3]);
      if (l2on) red[(1 * 3 + ks - 1) * Bsz + b] = make_float4(a2[0], a2[1], a2[2], a2[3]);
      if (l3on) red[(2 * 3 + ks - 1) * Bsz + b] = make_float4(a3[0], a3[1], a3[2], a3[3]);
    }
    __syncthreads();

    if (ks == 0) {
      if (l1on) {
#pragma unroll
        for (int q = 0; q < 3; ++q) {
          float4 r = red[(0 * 3 + q) * Bsz + b];
          a1[0] += r.x; a1[1] += r.y; a1[2] += r.z; a1[3] += r.w;
        }
        fb_store4(sb + fb_srow(swr, 0, b) + h0, fb_lif(v1, a1));
      }
      if (l2on) {
#pragma unroll
        for (int q = 0; q < 3; ++q) {
          float4 r = red[(1 * 3 + q) * Bsz + b];
          a2[0] += r.x; a2[1] += r.y; a2[2] += r.z; a2[3] += r.w;
        }
        fb_store4(sb + fb_srow(swr, 1, b) + h0, fb_lif(v2, a2));
      }
      if (l3on) {
#pragma unroll
        for (int q = 0; q < 3; ++q) {
          float4 r = red[(2 * 3 + q) * Bsz + b];
          a3[0] += r.x; a3[1] += r.y; a3[2] += r.z; a3[3] += r.w;
        }
        fb_store4(sb + fb_srow(swr, 2, b) + h0, fb_lif(v3, a3));
      }
    }

    asm volatile("s_waitcnt vmcnt(0)" ::: "memory");
    __syncthreads();
    if (tid == 0) {
      __hip_atomic_fetch_add(bar, 1u, __ATOMIC_RELAXED, __HIP_MEMORY_SCOPE_AGENT);
      const unsigned tgt = (unsigned)(p + 1) * FB_NBLK;
      while (__hip_atomic_load(bar, __ATOMIC_RELAXED, __HIP_MEMORY_SCOPE_AGENT) < tgt) {}
    }
    __syncthreads();
  }

  if (ks == 0) {
    float4 o = make_float4(expf(v3[0]), expf(v3[1]), expf(v3[2]), expf(v3[3]));
    *(float4*)(out + (size_t)b * Hn + h0) = o;
  }
}

// ======================= launcher =======================
extern "C" void kernel_launch(void* const* d_in, const int* in_sizes, int n_in,
                              void* d_out, int out_size, void* d_ws, size_t ws_size,
                              hipStream_t stream) {
  const float* x  = (const float*)d_in[0];
  const float* W1 = (const float*)d_in[1];
  const float* R1 = (const float*)d_in[2];
  const float* W2 = (const float*)d_in[3];
  const float* R2 = (const float*)d_in[4];
  const float* W3 = (const float*)d_in[5];
  const float* R3 = (const float*)d_in[6];
  float* out = (float*)d_out;
  unsigned char* ws = (unsigned char*)d_ws;

  hipFuncSetAttribute((const void*)snn_fb,
                      hipFuncAttributeMaxDynamicSharedMemorySize, (int)FB_SMEM);

  if (ws_size >= WS_NEED) {
    // bf16 weight prep + zero spike slots/barrier area
    hipLaunchKernelGGL(prep_w, dim3(20480), dim3(256), 0, stream,
                       R1, W2, R2, W3, R3, ws);
    hipMemsetAsync(ws + SB_OFF, 0, SB_BYTES + 4096, stream);
    void* args[] = { (void*)&x, (void*)&W1, (void*)&ws, (void*)&out };
    hipError_t e = hipLaunchCooperativeKernel((const void*)snn_mfma, dim3(NBLK),
                                              dim3(256), args, 0, stream);
    if (e == hipSuccess) return;
  }

  // fallback: proven VALU path (spikes at ws[0])
  unsigned char* sbytes = ws;
  unsigned* bar = (unsigned*)(ws + FB_SB_BYTES);
  hipMemsetAsync(ws, 0, FB_SB_BYTES + 64, stream);
  void* fargs[] = { (void*)&x, (void*)&W1, (void*)&R1, (void*)&W2, (void*)&R2,
                    (void*)&W3, (void*)&R3, (void*)&sbytes, (void*)&bar,
                    (void*)&out };
  hipLaunchCooperativeKernel((const void*)snn_fb, dim3(FB_NBLK), dim3(1024),
                             fargs, FB_SMEM, stream);
}

// Round 10
// 15405.638 us; speedup vs baseline: 3.6442x; 3.6442x over previous
//
#include <hip/hip_runtime.h>

// Problem constants
constexpr int Bsz = 256, Lf = 14, Tt = 500, Hn = 1000;
constexpr int HP = 1024, KP = 1024;     // padded h/k extents
constexpr int NG = 8, GBLK = 32;        // 8 groups x 32 blocks
constexpr int NBLK = NG * GBLK;         // 256

// d_ws layout
constexpr size_t W_MAT    = (size_t)HP * KP * 2;        // 2 MB bf16 per matrix
constexpr size_t W_SH     = (size_t)HP * KP;            // shorts per matrix
constexpr size_t SB_OFF   = 5 * W_MAT;                  // 10,485,760
// spike planes: [slot:2][layer:3][group:8][b:32][KP] bytes
constexpr size_t SB_BYTES = (size_t)2 * 3 * NG * GBLK * KP;  // 1,572,864
constexpr size_t BAR_OFF  = SB_OFF + SB_BYTES;
constexpr size_t WS_NEED  = BAR_OFF + 4096;

typedef __attribute__((ext_vector_type(8)))  short    short8;  // 8 bf16
typedef __attribute__((ext_vector_type(16))) float    f32x16;
typedef __attribute__((ext_vector_type(2)))  unsigned u32x2;
typedef __attribute__((ext_vector_type(4)))  unsigned u32x4v;

// ======================= prep kernel (bf16 weights) =======================
__device__ __forceinline__ unsigned short f2bf(float f) {
  unsigned u = __builtin_bit_cast(unsigned, f);
  unsigned r = (u + 0x7FFFu + ((u >> 16) & 1u)) >> 16;   // RNE
  return (unsigned short)r;
}

__global__ void prep_w(const float* __restrict__ R1, const float* __restrict__ W2,
                       const float* __restrict__ R2, const float* __restrict__ W3,
                       const float* __restrict__ R3, unsigned char* __restrict__ ws) {
  int id  = blockIdx.x * 256 + threadIdx.x;      // 5 * 2^20 threads
  int mat = id >> 20;
  int rem = id & 0xFFFFF;
  int h   = rem >> 10;
  int k   = rem & 1023;
  const float* src = (mat == 0) ? R1 : (mat == 1) ? W2 : (mat == 2) ? R2
                    : (mat == 3) ? W3 : R3;
  float v = (h < Hn && k < Hn) ? src[(size_t)h * Hn + k] : 0.f;
  ((unsigned short*)ws)[(size_t)mat * W_SH + (size_t)h * KP + k] = f2bf(v);
}

// ======================= main kernel helpers =======================
__device__ __forceinline__ short8 expand8(u32x2 d) {
  // 8 spike bytes (0/1) -> 8 bf16 (0.0/1.0). pair = b0 | b1<<16; *0x3F80.
  unsigned p0 = __umul24(((d[0] & 0xFFu)         | ((d[0] & 0xFF00u) << 8)), 0x3F80u);
  unsigned p1 = __umul24((((d[0] >> 16) & 0xFFu) | ((d[0] >> 24) << 16)),    0x3F80u);
  unsigned p2 = __umul24(((d[1] & 0xFFu)         | ((d[1] & 0xFF00u) << 8)), 0x3F80u);
  unsigned p3 = __umul24((((d[1] >> 16) & 0xFFu) | ((d[1] >> 24) << 16)),    0x3F80u);
  u32x4v u = {p0, p1, p2, p3};
  return __builtin_bit_cast(short8, u);
}

__device__ __forceinline__ f32x16 MF(short8 a, const unsigned short* wp, f32x16 c) {
  short8 b = *(const short8*)wp;
  return __builtin_amdgcn_mfma_f32_32x32x16_bf16(a, b, c, 0, 0, 0);
}

// 16 coherent dwordx2 spike loads (one 256-k quarter of one stream), one wait.
__device__ __forceinline__ void spk16(const unsigned char* p, u32x2 d[16]) {
  asm volatile(
    "global_load_dwordx2 %0, %16, off sc0 sc1\n\t"
    "global_load_dwordx2 %1, %16, off offset:16 sc0 sc1\n\t"
    "global_load_dwordx2 %2, %16, off offset:32 sc0 sc1\n\t"
    "global_load_dwordx2 %3, %16, off offset:48 sc0 sc1\n\t"
    "global_load_dwordx2 %4, %16, off offset:64 sc0 sc1\n\t"
    "global_load_dwordx2 %5, %16, off offset:80 sc0 sc1\n\t"
    "global_load_dwordx2 %6, %16, off offset:96 sc0 sc1\n\t"
    "global_load_dwordx2 %7, %16, off offset:112 sc0 sc1\n\t"
    "global_load_dwordx2 %8, %16, off offset:128 sc0 sc1\n\t"
    "global_load_dwordx2 %9, %16, off offset:144 sc0 sc1\n\t"
    "global_load_dwordx2 %10, %16, off offset:160 sc0 sc1\n\t"
    "global_load_dwordx2 %11, %16, off offset:176 sc0 sc1\n\t"
    "global_load_dwordx2 %12, %16, off offset:192 sc0 sc1\n\t"
    "global_load_dwordx2 %13, %16, off offset:208 sc0 sc1\n\t"
    "global_load_dwordx2 %14, %16, off offset:224 sc0 sc1\n\t"
    "global_load_dwordx2 %15, %16, off offset:240 sc0 sc1\n\t"
    "s_waitcnt vmcnt(0)"
    : "=&v"(d[0]), "=&v"(d[1]), "=&v"(d[2]), "=&v"(d[3]),
      "=&v"(d[4]), "=&v"(d[5]), "=&v"(d[6]), "=&v"(d[7]),
      "=&v"(d[8]), "=&v"(d[9]), "=&v"(d[10]), "=&v"(d[11]),
      "=&v"(d[12]), "=&v"(d[13]), "=&v"(d[14]), "=&v"(d[15])
    : "v"(p) : "memory");
}

// acc += (256-k quarter of one spike stream) x (weight rows)
__device__ __forceinline__ void stream16(f32x16& acc, const unsigned char* sp,
                                         const unsigned short* wp) {
  u32x2 d[16];
  spk16(sp, d);
  __builtin_amdgcn_sched_barrier(0);
#pragma unroll
  for (int kc = 0; kc < 16; ++kc)
    acc = MF(expand8(d[kc]), wp + kc * 16, acc);
}

// ======================= main cooperative kernel =======================
__global__ void __launch_bounds__(256, 1)
snn_mfma(const float* __restrict__ x, const float* __restrict__ W1,
         unsigned char* __restrict__ ws, float* __restrict__ out)
{
  // [0,9216): reduce (3 waves x 3 tiles x 1024, [j][lane] layout)
  // [9216,12288): F tiles (3 x 32b x 32h)
  __shared__ float lds[12288];

  const int tid = threadIdx.x;
  const int l   = tid & 63;
  const int w   = tid >> 6;       // wave 0..3 = k-quarter
  const int lr  = l & 31;         // A-row (b) / B-col (h)
  const int lg  = l >> 5;         // k lane-group
  const int blk = blockIdx.x;
  const int g   = blk >> 5;       // group (batch slice), spread over XCDs
  const int r   = blk & 31;       // rank: same-r blocks share weights + XCD
  const int b0  = g * GBLK;

  unsigned char* sb  = ws + SB_OFF;
  unsigned*      bar = (unsigned*)(ws + BAR_OFF);
  const unsigned short* wb = (const unsigned short*)ws;

  // 3 row-tiles per block: rt = r*3+i; layer = rt>>5, h0 = (rt&31)*32
  int lay[3], hh[3], plA[3], plB[3];
  const unsigned short *wA[3], *wB[3];
#pragma unroll
  for (int i = 0; i < 3; ++i) {
    const int rt = r * 3 + i;
    lay[i] = rt >> 5;
    hh[i]  = (rt & 31) * 32;
    const size_t wl = (size_t)(hh[i] + lr) * KP + w * 256 + lg * 8;
    if (lay[i] == 0)      { wA[i] = wb + 0*W_SH + wl; wB[i] = wb;            plA[i] = 0; plB[i] = 0; }
    else if (lay[i] == 1) { wA[i] = wb + 1*W_SH + wl; wB[i] = wb + 2*W_SH + wl; plA[i] = 0; plB[i] = 1; }
    else                  { wA[i] = wb + 3*W_SH + wl; wB[i] = wb + 4*W_SH + wl; plA[i] = 1; plB[i] = 2; }
  }

  f32x16 v[3];
#pragma unroll
  for (int i = 0; i < 3; ++i)
#pragma unroll
    for (int j = 0; j < 16; ++j) v[i][j] = 0.f;

#pragma unroll 1
  for (int p = 0; p < Tt + 2; ++p) {
    const int srd = (p + 1) & 1;
    const int swr = p & 1;

    // ---- F = x@W1^T for layer-0 tiles (k=14, VALU) ----
#pragma unroll
    for (int i = 0; i < 3; ++i) {
      if (lay[i] != 0) continue;            // uniform per block
      const int fh = tid & 31;
      const int fb = tid >> 5;              // +8q rows
      float F0 = 0.f, F1 = 0.f, F2 = 0.f, F3 = 0.f;
      if (p < Tt) {
        const int hrow = hh[i] + fh;
        const float* xq0 = x + (size_t)(b0 + fb)      * (Lf * Tt) + p;
        const float* xq1 = x + (size_t)(b0 + fb + 8)  * (Lf * Tt) + p;
        const float* xq2 = x + (size_t)(b0 + fb + 16) * (Lf * Tt) + p;
        const float* xq3 = x + (size_t)(b0 + fb + 24) * (Lf * Tt) + p;
        const float* w1p = W1 + (size_t)hrow * Lf;
#pragma unroll
        for (int t = 0; t < Lf; ++t) {
          const float wv = (hrow < Hn) ? w1p[t] : 0.f;
          F0 = fmaf(xq0[(size_t)t * Tt], wv, F0);
          F1 = fmaf(xq1[(size_t)t * Tt], wv, F1);
          F2 = fmaf(xq2[(size_t)t * Tt], wv, F2);
          F3 = fmaf(xq3[(size_t)t * Tt], wv, F3);
        }
      }
      float* Fp = &lds[9216 + i * 1024 + fb * 32 + fh];
      Fp[0]      = F0;
      Fp[8 * 32] = F1;
      Fp[16 * 32] = F2;
      Fp[24 * 32] = F3;
    }

    // ---- MFMA: 3 tiles, k-quarter per wave ----
    f32x16 acc[3];
#pragma unroll
    for (int i = 0; i < 3; ++i) {
#pragma unroll
      for (int j = 0; j < 16; ++j) acc[i][j] = 0.f;
      const size_t lanes = (size_t)lr * KP + w * 256 + lg * 8;
      const unsigned char* pA =
          sb + ((((size_t)srd * 3 + plA[i]) * NG + g) << 15) + lanes;
      stream16(acc[i], pA, wA[i]);
      if (lay[i] != 0) {
        const unsigned char* pB =
            sb + ((((size_t)srd * 3 + plB[i]) * NG + g) << 15) + lanes;
        stream16(acc[i], pB, wB[i]);
      }
    }

    // ---- cross-wave reduce ([j][lane] layout, conflict-free) ----
    if (w != 0) {
      float* dp = &lds[(w - 1) * 3 * 1024 + l];
#pragma unroll
      for (int i = 0; i < 3; ++i)
#pragma unroll
        for (int j = 0; j < 16; ++j) dp[i * 1024 + j * 64] = acc[i][j];
    }
    __syncthreads();

    if (w == 0) {
#pragma unroll
      for (int i = 0; i < 3; ++i) {
        unsigned char* o =
            sb + ((((size_t)swr * 3 + lay[i]) * NG + g) << 15) + hh[i] + lr;
#pragma unroll
        for (int j = 0; j < 16; ++j) {
          const int row = (j & 3) + 8 * (j >> 2) + 4 * lg;   // b-row of C tile
          float a = acc[i][j];
#pragma unroll
          for (int ww = 0; ww < 3; ++ww)
            a += lds[(ww * 3 + i) * 1024 + j * 64 + l];
          const float F = (lay[i] == 0) ? lds[9216 + i * 1024 + row * 32 + lr] : 0.f;
          const float vn = 0.5f * (v[i][j] + a + F);
          const unsigned c = (vn >= 1.0f) ? 1u : 0u;
          v[i][j] = c ? 0.f : vn;
          asm volatile("global_store_byte %0, %1, off sc0 sc1"
                       :: "v"(o + (size_t)row * KP), "v"(c) : "memory");
        }
      }
    }

    // ---- group-local barrier (32 blocks; groups fully independent) ----
    asm volatile("s_waitcnt vmcnt(0)" ::: "memory");   // spike stores visible
    __syncthreads();
    if (tid == 0) {
      unsigned* cnt = bar + g * 32;          // 128B apart per group
      unsigned* rel = bar + 512 + g * 32;    // release lines, separate region
      unsigned old = __hip_atomic_fetch_add(cnt, 1u, __ATOMIC_RELAXED,
                                            __HIP_MEMORY_SCOPE_AGENT);
      if (old == (unsigned)(p + 1) * GBLK - 1u)
        __hip_atomic_store(rel, (unsigned)(p + 1), __ATOMIC_RELAXED,
                           __HIP_MEMORY_SCOPE_AGENT);
      while (__hip_atomic_load(rel, __ATOMIC_RELAXED,
                               __HIP_MEMORY_SCOPE_AGENT) < (unsigned)(p + 1))
        __builtin_amdgcn_s_sleep(1);
    }
    __syncthreads();
  }

  // ---- output: exp(final v3) from layer-2 tiles ----
  if (w == 0) {
#pragma unroll
    for (int i = 0; i < 3; ++i) {
      if (lay[i] != 2) continue;
      const int h = hh[i] + lr;
      if (h < Hn) {
#pragma unroll
        for (int j = 0; j < 16; ++j) {
          const int row = (j & 3) + 8 * (j >> 2) + 4 * lg;
          out[(size_t)(b0 + row) * Hn + h] = expf(v[i][j]);
        }
      }
    }
  }
}

// ======================= launcher =======================
extern "C" void kernel_launch(void* const* d_in, const int* in_sizes, int n_in,
                              void* d_out, int out_size, void* d_ws, size_t ws_size,
                              hipStream_t stream) {
  const float* x  = (const float*)d_in[0];
  const float* W1 = (const float*)d_in[1];
  const float* R1 = (const float*)d_in[2];
  const float* W2 = (const float*)d_in[3];
  const float* R2 = (const float*)d_in[4];
  const float* W3 = (const float*)d_in[5];
  const float* R3 = (const float*)d_in[6];
  float* out = (float*)d_out;
  unsigned char* ws = (unsigned char*)d_ws;

  (void)ws_size;  // r8 proved ws_size >= 12.06 MB (MFMA path ran)

  // bf16 weight prep + zero spike slots / barrier area
  hipLaunchKernelGGL(prep_w, dim3(20480), dim3(256), 0, stream,
                     R1, W2, R2, W3, R3, ws);
  hipMemsetAsync(ws + SB_OFF, 0, SB_BYTES + 4096, stream);

  void* args[] = { (void*)&x, (void*)&W1, (void*)&ws, (void*)&out };
  hipLaunchCooperativeKernel((const void*)snn_mfma, dim3(NBLK), dim3(256),
                             args, 0, stream);
}